// Round 17
// baseline (98.267 us; speedup 1.0000x reference)
//
#include <hip/hip_runtime.h>
#include <hip/hip_bf16.h>
#include <hip/hip_fp16.h>
#include <math.h>

#define N_NODES 10000
#define DIM 128
#define N_EDGES 640000
#define BN_EPS 1e-3f

#define QUARTER 2500
#define QPAD 3072             // padded quarter stride
#define PART_BLOCKS 250       // edge chunks: 640000 / 2560
#define EDGES_PER_PART 2560
#define SCAT_GRID 1000        // 250 chunks x 4 quarters
#define MSG64_BLOCKS 157      // ceil(10000 / 64)
#define SU_BLOCKS 1250        // 10000 / 8

typedef _Float16 half8 __attribute__((ext_vector_type(8)));
typedef float f32x4 __attribute__((ext_vector_type(4)));

__device__ __forceinline__ float gelu_exact(float x) {
  return 0.5f * x * (1.0f + erff(x * 0.70710678f));
}

// Swizzled LDS tile: [16 rows][128 cols] f16, row stride 256 B.
__device__ __forceinline__ int lds_swz(int row, int colbyte) {
  return ((row * 256 + colbyte) ^ ((row & 7) << 4));
}

// f32 -> fp8 e4m3 (OCP on gfx950), single value via HW pack instruction.
__device__ __forceinline__ unsigned char f32_to_fp8(float v) {
  unsigned pk = __builtin_amdgcn_cvt_pk_fp8_f32(v, v, 0, false);
  return (unsigned char)(pk & 0xffu);
}

// Pack (nbr, weight) into one u32: high 16 = nbr, low 16 = bf16(w) (RTN).
__device__ __forceinline__ unsigned pack_edge(int nbr, float w) {
  return ((unsigned)nbr << 16) | ((__float_as_uint(w) + 0x8000u) >> 16);
}

struct FoldAll {
  const float* g[4];
  const float* bb[4];
  const float* m[4];
  const float* v[4];
  const float* W[4];
  const float* bias[4];
  _Float16* pk[4];
  float* bf[4];
  int din[4];
  int S[4];  // K/32
};

// K1: grid = 44 + PART_BLOCKS blocks x 256 thr.
// b in [0,40): pack W fragments (f16, B-frag layout, BN-scale folded).
// b in [40,44): folded bias; block 40+p also zeroes qtot (p==0) and the
//   padded tail of histq quarter p.
// b >= 44: single-pass PACKED-u16 LDS histogram (20 KB) of chunk eb ->
//   u8 partial rows in quarter-major layout part[(q*250+eb)*2500 + bp].
__global__ __launch_bounds__(256) void fold_hist_kernel(FoldAll fa,
                                                        const int* __restrict__ node_idx,
                                                        unsigned char* __restrict__ part,
                                                        int* __restrict__ histq,
                                                        int* __restrict__ qtot) {
  __shared__ int lh2[N_NODES / 2];
  __shared__ float t_sh[256];
  __shared__ float bpart[128];
  int b = blockIdx.x, t = threadIdx.x;
  if (b >= 44) {
    int eb = b - 44;
    for (int i = t; i < N_NODES / 2; i += 256) lh2[i] = 0;
    __syncthreads();
    int base0 = eb * EDGES_PER_PART;
#pragma unroll
    for (int s = 0; s < 3; ++s) {
      int off = s * 1024 + t * 4;
      if (off < EDGES_PER_PART) {
        int4 vv = *reinterpret_cast<const int4*>(&node_idx[base0 + off]);
        atomicAdd(&lh2[vv.x >> 1], 1 << ((vv.x & 1) << 4));
        atomicAdd(&lh2[vv.y >> 1], 1 << ((vv.y & 1) << 4));
        atomicAdd(&lh2[vv.z >> 1], 1 << ((vv.z & 1) << 4));
        atomicAdd(&lh2[vv.w >> 1], 1 << ((vv.w & 1) << 4));
      }
    }
    __syncthreads();
    for (int i = t; i < N_NODES; i += 256) {
      int c = (lh2[i >> 1] >> ((i & 1) << 4)) & 0xFFFF;
      int q = i / QUARTER;
      int bp = i - q * QUARTER;
      part[(size_t)(q * PART_BLOCKS + eb) * QUARTER + bp] = (unsigned char)c;
    }
    return;
  }
  if (b >= 40) {
    int p = b - 40;
    if (p == 0 && t < 4) qtot[t] = 0;
    for (int i = t; i < QPAD - QUARTER; i += 256) histq[p * QPAD + QUARTER + i] = 0;
    int din = fa.din[p];
    const float* W = fa.W[p];
    for (int k = t; k < din; k += 256) {
      float sc = fa.g[p][k] * rsqrtf(fa.v[p][k] + BN_EPS);
      t_sh[k] = fa.bb[p][k] - fa.m[p][k] * sc;
    }
    __syncthreads();
    int j = t & 127, kh = t >> 7;
    int half = din >> 1;
    float acc = 0.f;
    for (int k = kh * half; k < (kh + 1) * half; ++k)
      acc = fmaf(t_sh[k], W[k * 128 + j], acc);
    if (kh == 1) bpart[j] = acc;
    __syncthreads();
    if (kh == 0) fa.bf[p][j] = acc + bpart[j] + fa.bias[p][j];
    return;
  }
  int p, lf;
  if (b < 8)       { p = 0; lf = b * 256 + t; }
  else if (b < 16) { p = 1; lf = (b - 8) * 256 + t; }
  else if (b < 32) { p = 2; lf = (b - 16) * 256 + t; }
  else             { p = 3; lf = (b - 32) * 256 + t; }
  int S = fa.S[p];
  int l = lf & 63;
  int fs = lf >> 6;
  int f = fs & 7, s = fs >> 3;
  if (s >= S) return;
  const float* W = fa.W[p];
  const float* g = fa.g[p];
  const float* v = fa.v[p];
  int k0 = s * 32 + (l >> 4) * 8;
  int col = f * 16 + (l & 15);
  half8 h;
#pragma unroll
  for (int i = 0; i < 8; ++i) {
    int k = k0 + i;
    float sc = g[k] * rsqrtf(v[k] + BN_EPS);
    h[i] = (_Float16)(sc * W[k * 128 + col]);
  }
  *reinterpret_cast<half8*>(fa.pk[p] + (size_t)lf * 8) = h;
}

// K2: merge only — grid 40 x 256 thr. Per bin: prefix over 250 u8 partials;
// total -> histq[q*QPAD + bp]; per-quarter totals into qtot.
__global__ __launch_bounds__(256) void merge_kernel(
    unsigned char* __restrict__ part, int* __restrict__ histq,
    int* __restrict__ qtot) {
  __shared__ int qsum[4];
  int b = blockIdx.x, t = threadIdx.x;
  int bin = b * 256 + t;
  int sum = 0;
  int q = 0;
  if (bin < N_NODES) {
    q = bin / QUARTER;
    int bp = bin - q * QUARTER;
    unsigned char* col = part + (size_t)q * PART_BLOCKS * QUARTER + bp;
#pragma unroll
    for (int c = 0; c < PART_BLOCKS; c += 25) {
      int vals[25];
#pragma unroll
      for (int i = 0; i < 25; ++i) vals[i] = col[(size_t)(c + i) * QUARTER];
#pragma unroll
      for (int i = 0; i < 25; ++i) {
        col[(size_t)(c + i) * QUARTER] = (unsigned char)sum;
        sum += vals[i];
      }
    }
    histq[q * QPAD + bp] = sum;
  }
  if (t < 4) qsum[t] = 0;
  __syncthreads();
  if (bin < N_NODES) atomicAdd(&qsum[q], sum);
  __syncthreads();
  if (t < 4) atomicAdd(&qtot[t], qsum[t]);
}

// K3: scatter (blocks [0,1000)) + per-node message (blocks [1000,1157)).
// Scatter block (eb, q): scans only its quarter, offsets by qpre from qtot;
// eb==0 blocks write row_start; then scatters chunk eb's edges (4-byte
// packed records) via LDS atomics.
// Msg blocks: f16 MFMA FFN, 4 waves x 16 rows, M stored fp8.
__global__ __launch_bounds__(256) void scatter_msg_kernel(
    const int* __restrict__ node_idx, const int* __restrict__ nbr_idx,
    const float* __restrict__ ew, const int* __restrict__ histq,
    const int* __restrict__ qtot,
    const unsigned char* __restrict__ part, unsigned* __restrict__ edge_s,
    int* __restrict__ row_start,
    const float* __restrict__ x,
    const _Float16* __restrict__ W1pk, const float* __restrict__ b1f,
    const _Float16* __restrict__ W2pk, const float* __restrict__ b2f,
    unsigned char* __restrict__ M8) {
  __shared__ __align__(16) char shmem[4 * 4096];  // union: scatter 11 KB / msg 16 KB
  int bk = blockIdx.x, t = threadIdx.x;
  if (bk >= SCAT_GRID) {
    // ---- msg path ----
    char* lds_raw = shmem;
    int wid = t >> 6, lane = t & 63;
    int r = lane & 15, g = lane >> 4;
    int row0 = (bk - SCAT_GRID) * 64 + wid * 16;
    char* lbase = lds_raw + wid * 4096;

    int arow = row0 + r;
    if (arow > N_NODES - 1) arow = N_NODES - 1;
    const float* xp = x + (size_t)arow * DIM;

    half8 a[4];
#pragma unroll
    for (int s = 0; s < 4; ++s) {
      float4 lo = *reinterpret_cast<const float4*>(xp + s * 32 + g * 8);
      float4 hi = *reinterpret_cast<const float4*>(xp + s * 32 + g * 8 + 4);
      half8 h;
      h[0] = (_Float16)lo.x; h[1] = (_Float16)lo.y; h[2] = (_Float16)lo.z; h[3] = (_Float16)lo.w;
      h[4] = (_Float16)hi.x; h[5] = (_Float16)hi.y; h[6] = (_Float16)hi.z; h[7] = (_Float16)hi.w;
      a[s] = h;
    }

    f32x4 zero = {0.f, 0.f, 0.f, 0.f};
    f32x4 acc[8];
#pragma unroll
    for (int f = 0; f < 8; ++f) acc[f] = zero;
#pragma unroll
    for (int f = 0; f < 8; ++f)
#pragma unroll
      for (int s = 0; s < 4; ++s) {
        half8 bfrag = *reinterpret_cast<const half8*>(W1pk + (size_t)((s * 8 + f) * 64 + lane) * 8);
        acc[f] = __builtin_amdgcn_mfma_f32_16x16x32_f16(a[s], bfrag, acc[f], 0, 0, 0);
      }

#pragma unroll
    for (int f = 0; f < 8; ++f) {
      int col = f * 16 + r;
      float bv = b1f[col];
#pragma unroll
      for (int j = 0; j < 4; ++j) {
        int rl = g * 4 + j;
        float gv = gelu_exact(acc[f][j] + bv);
        *reinterpret_cast<_Float16*>(lbase + lds_swz(rl, col * 2)) = (_Float16)gv;
      }
    }

    half8 a2[4];
#pragma unroll
    for (int s = 0; s < 4; ++s)
      a2[s] = *reinterpret_cast<const half8*>(lbase + lds_swz(r, (s * 32 + g * 8) * 2));

    f32x4 acc2[8];
#pragma unroll
    for (int f = 0; f < 8; ++f) acc2[f] = zero;
#pragma unroll
    for (int f = 0; f < 8; ++f)
#pragma unroll
      for (int s = 0; s < 4; ++s) {
        half8 bfrag = *reinterpret_cast<const half8*>(W2pk + (size_t)((s * 8 + f) * 64 + lane) * 8);
        acc2[f] = __builtin_amdgcn_mfma_f32_16x16x32_f16(a2[s], bfrag, acc2[f], 0, 0, 0);
      }

#pragma unroll
    for (int f = 0; f < 8; ++f) {
      int col = f * 16 + r;
      float bv = b2f[col];
#pragma unroll
      for (int j = 0; j < 4; ++j) {
        int grow = row0 + g * 4 + j;
        if (grow < N_NODES)
          M8[(size_t)grow * DIM + col] = f32_to_fp8(gelu_exact(acc2[f][j] + bv));
      }
    }
    return;
  }
  // ---- scatter path ----
  int* cur = reinterpret_cast<int*>(shmem);                    // QUARTER ints
  int* sums = reinterpret_cast<int*>(shmem + QUARTER * 4);     // 256 ints
  int eb = bk >> 2;
  int q = bk & 3;
  int qbase = q * QUARTER;
  const int PER = 12;  // 256 * 12 = 3072 = QPAD
  int i0 = t * PER;
  const int* hq = histq + q * QPAD;
  int lh[PER];
  int total = 0;
#pragma unroll
  for (int i = 0; i < PER; i += 4) {
    int4 h4 = *reinterpret_cast<const int4*>(&hq[i0 + i]);
    lh[i] = h4.x; lh[i + 1] = h4.y; lh[i + 2] = h4.z; lh[i + 3] = h4.w;
    total += h4.x + h4.y + h4.z + h4.w;
  }
  sums[t] = total;
  __syncthreads();
  for (int off = 1; off < 256; off <<= 1) {
    int v = (t >= off) ? sums[t - off] : 0;
    __syncthreads();
    sums[t] += v;
    __syncthreads();
  }
  int q0 = qtot[0], q1 = qtot[1], q2 = qtot[2];
  int qpre = (q >= 1 ? q0 : 0) + (q >= 2 ? q1 : 0) + (q >= 3 ? q2 : 0);
  int running = qpre + sums[t] - total;  // global exclusive prefix at bin i0
  const unsigned char* prow = part + (size_t)(q * PART_BLOCKS + eb) * QUARTER;
  bool wrs = (eb == 0);
#pragma unroll
  for (int i = 0; i < PER; ++i) {
    int idx = i0 + i;
    if (idx < QUARTER) {
      cur[idx] = running + (int)prow[idx];
      if (wrs) row_start[qbase + idx] = running;
      running += lh[i];
    }
  }
  if (bk == 0 && t == 0) row_start[N_NODES] = N_EDGES;
  __syncthreads();

  int base0 = eb * EDGES_PER_PART;
#pragma unroll
  for (int s = 0; s < 3; ++s) {
    int off = s * 1024 + t * 4;
    if (off >= EDGES_PER_PART) break;
    int base = base0 + off;
    int4 ni = *reinterpret_cast<const int4*>(&node_idx[base]);
    int4 nb = *reinterpret_cast<const int4*>(&nbr_idx[base]);
    float4 wv = *reinterpret_cast<const float4*>(&ew[base]);
    unsigned d0 = (unsigned)(ni.x - qbase);
    unsigned d1 = (unsigned)(ni.y - qbase);
    unsigned d2 = (unsigned)(ni.z - qbase);
    unsigned d3 = (unsigned)(ni.w - qbase);
    if (d0 < QUARTER) {
      int p0 = atomicAdd(&cur[d0], 1);
      edge_s[p0] = pack_edge(nb.x, wv.x);
    }
    if (d1 < QUARTER) {
      int p1 = atomicAdd(&cur[d1], 1);
      edge_s[p1] = pack_edge(nb.y, wv.y);
    }
    if (d2 < QUARTER) {
      int p2 = atomicAdd(&cur[d2], 1);
      edge_s[p2] = pack_edge(nb.z, wv.z);
    }
    if (d3 < QUARTER) {
      int p3 = atomicAdd(&cur[d3], 1);
      edge_s[p3] = pack_edge(nb.w, wv.w);
    }
  }
}

// K4: fused spmm + update. grid = 1250 blocks x 256 thr, 8 rows/block.
// Phase 1: 32 thr/row = 4 edge-slices x 8 col-subs, 16 B fp8 gathers,
//   4-edge batches with next-batch edge prefetch; packed 4 B edge records
//   (nbr<<16 | bf16 w); HW cvt_pk_f32_fp8 dequant; slice partials via f32
//   LDS scratch; agg f16 into swizzled tile rows 0..7.
// Phase 2 (4 waves): MFMA on a 16-row tile with rows 8-15 zero-padded;
//   U1/U2 output fragments split 2-per-wave.
__global__ __launch_bounds__(256) void spmm_update_kernel(
    const int* __restrict__ row_start, const unsigned* __restrict__ edge_s,
    const unsigned char* __restrict__ M8, const float* __restrict__ x,
    const _Float16* __restrict__ U1pk, const float* __restrict__ bu1,
    const _Float16* __restrict__ U2pk, const float* __restrict__ bu2,
    float* __restrict__ out) {
  __shared__ float scratch[3][8][128];
  __shared__ char tile[4096];
  int t = threadIdx.x;
  int row0 = blockIdx.x * 8;

  {
    int r = t >> 5;       // 0..7 local row
    int q = t & 31;
    int slice = q >> 3;   // 0..3
    int sub = q & 7;      // cols sub*16 .. sub*16+15
    int row = row0 + r;
    int s = row_start[row];
    int e_end = row_start[row + 1];
    float acc[16];
#pragma unroll
    for (int c = 0; c < 16; ++c) acc[c] = 0.f;
    const unsigned char* Mb = M8 + sub * 16;
    int base = s + slice * 4;
    unsigned pk[4];
#pragma unroll
    for (int k = 0; k < 4; ++k) {
      int e = base + k;
      pk[k] = edge_s[(e < e_end) ? e : s];
      if (e >= e_end) pk[k] &= 0xFFFF0000u;  // weight -> 0 for padded lanes
    }
    for (; base < e_end; base += 16) {
      unsigned pkn[4];
      int nb = base + 16;
#pragma unroll
      for (int k = 0; k < 4; ++k) {
        int e = nb + k;
        pkn[k] = edge_s[(e < e_end) ? e : s];
        if (e >= e_end) pkn[k] &= 0xFFFF0000u;
      }
      uint4 raw[4];
#pragma unroll
      for (int k = 0; k < 4; ++k)
        raw[k] = *reinterpret_cast<const uint4*>(Mb + (size_t)(pk[k] >> 16) * DIM);
#pragma unroll
      for (int k = 0; k < 4; ++k) {
        float w = __uint_as_float(pk[k] << 16);
        const unsigned* u32s = reinterpret_cast<const unsigned*>(&raw[k]);
#pragma unroll
        for (int qq = 0; qq < 4; ++qq) {
          auto f01 = __builtin_amdgcn_cvt_pk_f32_fp8(u32s[qq], false);
          auto f23 = __builtin_amdgcn_cvt_pk_f32_fp8(u32s[qq], true);
          acc[4 * qq + 0] = fmaf(w, f01[0], acc[4 * qq + 0]);
          acc[4 * qq + 1] = fmaf(w, f01[1], acc[4 * qq + 1]);
          acc[4 * qq + 2] = fmaf(w, f23[0], acc[4 * qq + 2]);
          acc[4 * qq + 3] = fmaf(w, f23[1], acc[4 * qq + 3]);
        }
      }
#pragma unroll
      for (int k = 0; k < 4; ++k) pk[k] = pkn[k];
    }
    if (slice >= 1) {
      float* dst = &scratch[slice - 1][r][sub * 16];
      *reinterpret_cast<float4*>(dst) = make_float4(acc[0], acc[1], acc[2], acc[3]);
      *reinterpret_cast<float4*>(dst + 4) = make_float4(acc[4], acc[5], acc[6], acc[7]);
      *reinterpret_cast<float4*>(dst + 8) = make_float4(acc[8], acc[9], acc[10], acc[11]);
      *reinterpret_cast<float4*>(dst + 12) = make_float4(acc[12], acc[13], acc[14], acc[15]);
    }
    __syncthreads();
    if (slice == 0) {
#pragma unroll
      for (int sl = 0; sl < 3; ++sl) {
        const float* src = &scratch[sl][r][sub * 16];
#pragma unroll
        for (int c = 0; c < 16; c += 4) {
          float4 o = *reinterpret_cast<const float4*>(src + c);
          acc[c] += o.x; acc[c + 1] += o.y; acc[c + 2] += o.z; acc[c + 3] += o.w;
        }
      }
      int cnt = e_end - s;
      float inv = 1.f / (float)(cnt > 0 ? cnt : 1);
      half8 hlo, hhi;
#pragma unroll
      for (int c = 0; c < 8; ++c) hlo[c] = (_Float16)(acc[c] * inv);
#pragma unroll
      for (int c = 0; c < 8; ++c) hhi[c] = (_Float16)(acc[8 + c] * inv);
      *reinterpret_cast<half8*>(tile + lds_swz(r, sub * 32)) = hlo;
      *reinterpret_cast<half8*>(tile + lds_swz(r, sub * 32 + 16)) = hhi;
    }
  }
  __syncthreads();

  int wid = t >> 6, lane = t & 63;
  int r = lane & 15, g = lane >> 4;
  half8 hzero;
#pragma unroll
  for (int i = 0; i < 8; ++i) hzero[i] = (_Float16)0.f;

  half8 a[8];
#pragma unroll
  for (int s = 0; s < 8; ++s) a[s] = hzero;
  if (r < 8) {
    const float* xp = x + (size_t)(row0 + r) * DIM;
#pragma unroll
    for (int s = 0; s < 4; ++s) {
      float4 lo = *reinterpret_cast<const float4*>(xp + s * 32 + g * 8);
      float4 hi = *reinterpret_cast<const float4*>(xp + s * 32 + g * 8 + 4);
      half8 h;
      h[0] = (_Float16)lo.x; h[1] = (_Float16)lo.y; h[2] = (_Float16)lo.z; h[3] = (_Float16)lo.w;
      h[4] = (_Float16)hi.x; h[5] = (_Float16)hi.y; h[6] = (_Float16)hi.z; h[7] = (_Float16)hi.w;
      a[s] = h;
    }
#pragma unroll
    for (int s = 0; s < 4; ++s)
      a[4 + s] = *reinterpret_cast<const half8*>(tile + lds_swz(r, (s * 32 + g * 8) * 2));
  }
  __syncthreads();  // agg-tile reads done before layer-1 overwrites tile

  f32x4 zero = {0.f, 0.f, 0.f, 0.f};
  {
    f32x4 acc1[2];
    acc1[0] = zero; acc1[1] = zero;
#pragma unroll
    for (int fi = 0; fi < 2; ++fi) {
      int f = wid * 2 + fi;
#pragma unroll
      for (int s = 0; s < 8; ++s) {
        half8 bfrag = *reinterpret_cast<const half8*>(U1pk + (size_t)((s * 8 + f) * 64 + lane) * 8);
        acc1[fi] = __builtin_amdgcn_mfma_f32_16x16x32_f16(a[s], bfrag, acc1[fi], 0, 0, 0);
      }
    }
#pragma unroll
    for (int fi = 0; fi < 2; ++fi) {
      int f = wid * 2 + fi;
      int col = f * 16 + r;
      float bv = bu1[col];
#pragma unroll
      for (int j = 0; j < 4; ++j) {
        int rl = g * 4 + j;
        float gv = gelu_exact(acc1[fi][j] + bv);
        *reinterpret_cast<_Float16*>(tile + lds_swz(rl, col * 2)) = (_Float16)gv;
      }
    }
  }
  __syncthreads();  // layer-1 tile complete before layer-2 reads

  {
    half8 a2[4];
#pragma unroll
    for (int s = 0; s < 4; ++s) a2[s] = hzero;
    if (r < 8) {
#pragma unroll
      for (int s = 0; s < 4; ++s)
        a2[s] = *reinterpret_cast<const half8*>(tile + lds_swz(r, (s * 32 + g * 8) * 2));
    }
    f32x4 acc2[2];
    acc2[0] = zero; acc2[1] = zero;
#pragma unroll
    for (int fi = 0; fi < 2; ++fi) {
      int f = wid * 2 + fi;
#pragma unroll
      for (int s = 0; s < 4; ++s) {
        half8 bfrag = *reinterpret_cast<const half8*>(U2pk + (size_t)((s * 8 + f) * 64 + lane) * 8);
        acc2[fi] = __builtin_amdgcn_mfma_f32_16x16x32_f16(a2[s], bfrag, acc2[fi], 0, 0, 0);
      }
    }
#pragma unroll
    for (int fi = 0; fi < 2; ++fi) {
      int f = wid * 2 + fi;
      int col = f * 16 + r;
      float bv = bu2[col];
#pragma unroll
      for (int j = 0; j < 4; ++j) {
        int rloc = g * 4 + j;
        if (rloc < 8)
          out[(size_t)(row0 + rloc) * DIM + col] = gelu_exact(acc2[fi][j] + bv);
      }
    }
  }
}

extern "C" void kernel_launch(void* const* d_in, const int* in_sizes, int n_in,
                              void* d_out, int out_size, void* d_ws, size_t ws_size,
                              hipStream_t stream) {
  const float* x = (const float*)d_in[0];
  const int* edges = (const int*)d_in[1];
  const float* ew = (const float*)d_in[2];

  const int* node_idx = edges;            // edges[0, :]
  const int* nbr_idx = edges + N_EDGES;   // edges[1, :]

  char* wsp = (char*)d_ws;
  auto alloc = [&](size_t bytes) {
    char* p = wsp;
    wsp += (bytes + 255) & ~(size_t)255;
    return p;
  };
  unsigned char* M8 = (unsigned char*)alloc((size_t)N_NODES * DIM);
  _Float16* W1pk = (_Float16*)alloc(128 * 128 * 2);
  _Float16* W2pk = (_Float16*)alloc(128 * 128 * 2);
  _Float16* U1pk = (_Float16*)alloc(256 * 128 * 2);
  _Float16* U2pk = (_Float16*)alloc(128 * 128 * 2);
  float* b1f = (float*)alloc(128 * 4);
  float* b2f = (float*)alloc(128 * 4);
  float* bu1 = (float*)alloc(128 * 4);
  float* bu2 = (float*)alloc(128 * 4);
  int* histq = (int*)alloc(4 * QPAD * 4);
  int* qtot = (int*)alloc(4 * 4);
  int* row_start = (int*)alloc((N_NODES + 1) * 4);
  unsigned char* part = (unsigned char*)alloc((size_t)PART_BLOCKS * N_NODES);
  unsigned* edge_s = (unsigned*)alloc((size_t)N_EDGES * 4);

  FoldAll fa;
  fa.g[0] = (const float*)d_in[3];  fa.bb[0] = (const float*)d_in[4];
  fa.m[0] = (const float*)d_in[5];  fa.v[0] = (const float*)d_in[6];
  fa.W[0] = (const float*)d_in[7];  fa.bias[0] = (const float*)d_in[8];
  fa.g[1] = (const float*)d_in[9];  fa.bb[1] = (const float*)d_in[10];
  fa.m[1] = (const float*)d_in[11]; fa.v[1] = (const float*)d_in[12];
  fa.W[1] = (const float*)d_in[13]; fa.bias[1] = (const float*)d_in[14];
  fa.g[2] = (const float*)d_in[15]; fa.bb[2] = (const float*)d_in[16];
  fa.m[2] = (const float*)d_in[17]; fa.v[2] = (const float*)d_in[18];
  fa.W[2] = (const float*)d_in[19]; fa.bias[2] = (const float*)d_in[20];
  fa.g[3] = (const float*)d_in[21]; fa.bb[3] = (const float*)d_in[22];
  fa.m[3] = (const float*)d_in[23]; fa.v[3] = (const float*)d_in[24];
  fa.W[3] = (const float*)d_in[25]; fa.bias[3] = (const float*)d_in[26];
  fa.pk[0] = W1pk; fa.pk[1] = W2pk; fa.pk[2] = U1pk; fa.pk[3] = U2pk;
  fa.bf[0] = b1f; fa.bf[1] = b2f; fa.bf[2] = bu1; fa.bf[3] = bu2;
  fa.din[0] = 128; fa.din[1] = 128; fa.din[2] = 256; fa.din[3] = 128;
  fa.S[0] = 4; fa.S[1] = 4; fa.S[2] = 8; fa.S[3] = 4;

  fold_hist_kernel<<<44 + PART_BLOCKS, 256, 0, stream>>>(fa, node_idx, part, histq, qtot);
  merge_kernel<<<40, 256, 0, stream>>>(part, histq, qtot);
  scatter_msg_kernel<<<SCAT_GRID + MSG64_BLOCKS, 256, 0, stream>>>(
      node_idx, nbr_idx, ew, histq, qtot, part, edge_s, row_start,
      x, W1pk, b1f, W2pk, b2f, M8);
  spmm_update_kernel<<<SU_BLOCKS, 256, 0, stream>>>(
      row_start, edge_s, M8, x, U1pk, bu1, U2pk, bu2, (float*)d_out);
}

// Round 18
// 94.286 us; speedup vs baseline: 1.0422x; 1.0422x over previous
//
#include <hip/hip_runtime.h>
#include <hip/hip_bf16.h>
#include <hip/hip_fp16.h>
#include <math.h>

#define N_NODES 10000
#define DIM 128
#define N_EDGES 640000
#define BN_EPS 1e-3f

#define QUARTER 2500
#define QPAD 3072             // padded quarter stride
#define PART_BLOCKS 250       // edge chunks: 640000 / 2560
#define EDGES_PER_PART 2560
#define SCAT_GRID 1000        // 250 chunks x 4 quarters
#define MSG64_BLOCKS 157      // ceil(10000 / 64)
#define SU_BLOCKS 1250        // 10000 / 8

typedef _Float16 half8 __attribute__((ext_vector_type(8)));
typedef float f32x4 __attribute__((ext_vector_type(4)));

__device__ __forceinline__ float gelu_exact(float x) {
  return 0.5f * x * (1.0f + erff(x * 0.70710678f));
}

// Swizzled LDS tile: [16 rows][128 cols] f16, row stride 256 B.
__device__ __forceinline__ int lds_swz(int row, int colbyte) {
  return ((row * 256 + colbyte) ^ ((row & 7) << 4));
}

// f32 -> fp8 e4m3 (OCP on gfx950), single value via HW pack instruction.
__device__ __forceinline__ unsigned char f32_to_fp8(float v) {
  unsigned pk = __builtin_amdgcn_cvt_pk_fp8_f32(v, v, 0, false);
  return (unsigned char)(pk & 0xffu);
}

// Pack (nbr, weight) into one u32: high 16 = nbr, low 16 = bf16(w) (RTN).
__device__ __forceinline__ unsigned pack_edge(int nbr, float w) {
  return ((unsigned)nbr << 16) | ((__float_as_uint(w) + 0x8000u) >> 16);
}

struct FoldAll {
  const float* g[4];
  const float* bb[4];
  const float* m[4];
  const float* v[4];
  const float* W[4];
  const float* bias[4];
  _Float16* pk[4];
  float* bf[4];
  int din[4];
  int S[4];  // K/32
};

// K1: grid = 44 + PART_BLOCKS blocks x 256 thr.
// b in [0,40): pack W fragments (f16, B-frag layout, BN-scale folded).
// b in [40,44): folded bias; block 40+p also zeroes qtot (p==0) and the
//   padded tail of histq quarter p.
// b >= 44: single-pass PACKED-u16 LDS histogram (20 KB) of chunk eb ->
//   u8 partial rows in quarter-major layout part[(q*250+eb)*2500 + bp].
__global__ __launch_bounds__(256) void fold_hist_kernel(FoldAll fa,
                                                        const int* __restrict__ node_idx,
                                                        unsigned char* __restrict__ part,
                                                        int* __restrict__ histq,
                                                        int* __restrict__ qtot) {
  __shared__ int lh2[N_NODES / 2];
  __shared__ float t_sh[256];
  __shared__ float bpart[128];
  int b = blockIdx.x, t = threadIdx.x;
  if (b >= 44) {
    int eb = b - 44;
    for (int i = t; i < N_NODES / 2; i += 256) lh2[i] = 0;
    __syncthreads();
    int base0 = eb * EDGES_PER_PART;
#pragma unroll
    for (int s = 0; s < 3; ++s) {
      int off = s * 1024 + t * 4;
      if (off < EDGES_PER_PART) {
        int4 vv = *reinterpret_cast<const int4*>(&node_idx[base0 + off]);
        atomicAdd(&lh2[vv.x >> 1], 1 << ((vv.x & 1) << 4));
        atomicAdd(&lh2[vv.y >> 1], 1 << ((vv.y & 1) << 4));
        atomicAdd(&lh2[vv.z >> 1], 1 << ((vv.z & 1) << 4));
        atomicAdd(&lh2[vv.w >> 1], 1 << ((vv.w & 1) << 4));
      }
    }
    __syncthreads();
    for (int i = t; i < N_NODES; i += 256) {
      int c = (lh2[i >> 1] >> ((i & 1) << 4)) & 0xFFFF;
      int q = i / QUARTER;
      int bp = i - q * QUARTER;
      part[(size_t)(q * PART_BLOCKS + eb) * QUARTER + bp] = (unsigned char)c;
    }
    return;
  }
  if (b >= 40) {
    int p = b - 40;
    if (p == 0 && t < 4) qtot[t] = 0;
    for (int i = t; i < QPAD - QUARTER; i += 256) histq[p * QPAD + QUARTER + i] = 0;
    int din = fa.din[p];
    const float* W = fa.W[p];
    for (int k = t; k < din; k += 256) {
      float sc = fa.g[p][k] * rsqrtf(fa.v[p][k] + BN_EPS);
      t_sh[k] = fa.bb[p][k] - fa.m[p][k] * sc;
    }
    __syncthreads();
    int j = t & 127, kh = t >> 7;
    int half = din >> 1;
    float acc = 0.f;
    for (int k = kh * half; k < (kh + 1) * half; ++k)
      acc = fmaf(t_sh[k], W[k * 128 + j], acc);
    if (kh == 1) bpart[j] = acc;
    __syncthreads();
    if (kh == 0) fa.bf[p][j] = acc + bpart[j] + fa.bias[p][j];
    return;
  }
  int p, lf;
  if (b < 8)       { p = 0; lf = b * 256 + t; }
  else if (b < 16) { p = 1; lf = (b - 8) * 256 + t; }
  else if (b < 32) { p = 2; lf = (b - 16) * 256 + t; }
  else             { p = 3; lf = (b - 32) * 256 + t; }
  int S = fa.S[p];
  int l = lf & 63;
  int fs = lf >> 6;
  int f = fs & 7, s = fs >> 3;
  if (s >= S) return;
  const float* W = fa.W[p];
  const float* g = fa.g[p];
  const float* v = fa.v[p];
  int k0 = s * 32 + (l >> 4) * 8;
  int col = f * 16 + (l & 15);
  half8 h;
#pragma unroll
  for (int i = 0; i < 8; ++i) {
    int k = k0 + i;
    float sc = g[k] * rsqrtf(v[k] + BN_EPS);
    h[i] = (_Float16)(sc * W[k * 128 + col]);
  }
  *reinterpret_cast<half8*>(fa.pk[p] + (size_t)lf * 8) = h;
}

// K2: grid = 40 + MSG64_BLOCKS blocks x 256 thr.
// b in [0,40): merge — per bin, prefix over 250 u8 partials; total ->
//   histq[q*QPAD + bp]; per-quarter totals into qtot (LDS reduce + atomics).
// b >= 40: per-node message via f16 MFMA, 4 waves x 16 rows; M stored fp8.
__global__ __launch_bounds__(256) void merge_msg_kernel(
    unsigned char* __restrict__ part, int* __restrict__ histq,
    int* __restrict__ qtot,
    const float* __restrict__ x,
    const _Float16* __restrict__ W1pk, const float* __restrict__ b1f,
    const _Float16* __restrict__ W2pk, const float* __restrict__ b2f,
    unsigned char* __restrict__ M8) {
  __shared__ char lds_raw[4 * 4096];
  __shared__ int qsum[4];
  int b = blockIdx.x, t = threadIdx.x;
  if (b < 40) {
    int bin = b * 256 + t;
    int sum = 0;
    int q = 0;
    if (bin < N_NODES) {
      q = bin / QUARTER;
      int bp = bin - q * QUARTER;
      unsigned char* col = part + (size_t)q * PART_BLOCKS * QUARTER + bp;
#pragma unroll
      for (int c = 0; c < PART_BLOCKS; c += 25) {
        int vals[25];
#pragma unroll
        for (int i = 0; i < 25; ++i) vals[i] = col[(size_t)(c + i) * QUARTER];
#pragma unroll
        for (int i = 0; i < 25; ++i) {
          col[(size_t)(c + i) * QUARTER] = (unsigned char)sum;
          sum += vals[i];
        }
      }
      histq[q * QPAD + bp] = sum;
    }
    if (t < 4) qsum[t] = 0;
    __syncthreads();
    if (bin < N_NODES) atomicAdd(&qsum[q], sum);
    __syncthreads();
    if (t < 4) atomicAdd(&qtot[t], qsum[t]);
    return;
  }
  int wid = t >> 6, lane = t & 63;
  int r = lane & 15, g = lane >> 4;
  int row0 = (b - 40) * 64 + wid * 16;
  char* lbase = lds_raw + wid * 4096;

  int arow = row0 + r;
  if (arow > N_NODES - 1) arow = N_NODES - 1;
  const float* xp = x + (size_t)arow * DIM;

  half8 a[4];
#pragma unroll
  for (int s = 0; s < 4; ++s) {
    float4 lo = *reinterpret_cast<const float4*>(xp + s * 32 + g * 8);
    float4 hi = *reinterpret_cast<const float4*>(xp + s * 32 + g * 8 + 4);
    half8 h;
    h[0] = (_Float16)lo.x; h[1] = (_Float16)lo.y; h[2] = (_Float16)lo.z; h[3] = (_Float16)lo.w;
    h[4] = (_Float16)hi.x; h[5] = (_Float16)hi.y; h[6] = (_Float16)hi.z; h[7] = (_Float16)hi.w;
    a[s] = h;
  }

  f32x4 zero = {0.f, 0.f, 0.f, 0.f};
  f32x4 acc[8];
#pragma unroll
  for (int f = 0; f < 8; ++f) acc[f] = zero;
#pragma unroll
  for (int f = 0; f < 8; ++f)
#pragma unroll
    for (int s = 0; s < 4; ++s) {
      half8 bfrag = *reinterpret_cast<const half8*>(W1pk + (size_t)((s * 8 + f) * 64 + lane) * 8);
      acc[f] = __builtin_amdgcn_mfma_f32_16x16x32_f16(a[s], bfrag, acc[f], 0, 0, 0);
    }

#pragma unroll
  for (int f = 0; f < 8; ++f) {
    int col = f * 16 + r;
    float bv = b1f[col];
#pragma unroll
    for (int j = 0; j < 4; ++j) {
      int rl = g * 4 + j;
      float gv = gelu_exact(acc[f][j] + bv);
      *reinterpret_cast<_Float16*>(lbase + lds_swz(rl, col * 2)) = (_Float16)gv;
    }
  }

  half8 a2[4];
#pragma unroll
  for (int s = 0; s < 4; ++s)
    a2[s] = *reinterpret_cast<const half8*>(lbase + lds_swz(r, (s * 32 + g * 8) * 2));

  f32x4 acc2[8];
#pragma unroll
  for (int f = 0; f < 8; ++f) acc2[f] = zero;
#pragma unroll
  for (int f = 0; f < 8; ++f)
#pragma unroll
    for (int s = 0; s < 4; ++s) {
      half8 bfrag = *reinterpret_cast<const half8*>(W2pk + (size_t)((s * 8 + f) * 64 + lane) * 8);
      acc2[f] = __builtin_amdgcn_mfma_f32_16x16x32_f16(a2[s], bfrag, acc2[f], 0, 0, 0);
    }

#pragma unroll
  for (int f = 0; f < 8; ++f) {
    int col = f * 16 + r;
    float bv = b2f[col];
#pragma unroll
    for (int j = 0; j < 4; ++j) {
      int grow = row0 + g * 4 + j;
      if (grow < N_NODES)
        M8[(size_t)grow * DIM + col] = f32_to_fp8(gelu_exact(acc2[f][j] + bv));
    }
  }
}

// K3: quarter-partitioned scatter, grid = 1000 blocks x 256 thr.
// Block (eb, q): scans ONLY its quarter (3072 padded bins, 3 int4/thread),
// offsets by qpre from qtot; eb==0 blocks write row_start for their quarter;
// then scatters chunk eb's edges (4-byte packed records) via LDS atomics.
__global__ __launch_bounds__(256) void scatter_kernel(
    const int* __restrict__ node_idx, const int* __restrict__ nbr_idx,
    const float* __restrict__ ew, const int* __restrict__ histq,
    const int* __restrict__ qtot,
    const unsigned char* __restrict__ part, unsigned* __restrict__ edge_s,
    int* __restrict__ row_start) {
  __shared__ int cur[QUARTER];
  __shared__ int sums[256];
  int bk = blockIdx.x, t = threadIdx.x;
  int eb = bk >> 2;
  int q = bk & 3;
  int qbase = q * QUARTER;
  const int PER = 12;  // 256 * 12 = 3072 = QPAD
  int i0 = t * PER;
  const int* hq = histq + q * QPAD;
  int lh[PER];
  int total = 0;
#pragma unroll
  for (int i = 0; i < PER; i += 4) {
    int4 h4 = *reinterpret_cast<const int4*>(&hq[i0 + i]);
    lh[i] = h4.x; lh[i + 1] = h4.y; lh[i + 2] = h4.z; lh[i + 3] = h4.w;
    total += h4.x + h4.y + h4.z + h4.w;
  }
  sums[t] = total;
  __syncthreads();
  for (int off = 1; off < 256; off <<= 1) {
    int v = (t >= off) ? sums[t - off] : 0;
    __syncthreads();
    sums[t] += v;
    __syncthreads();
  }
  int q0 = qtot[0], q1 = qtot[1], q2 = qtot[2];
  int qpre = (q >= 1 ? q0 : 0) + (q >= 2 ? q1 : 0) + (q >= 3 ? q2 : 0);
  int running = qpre + sums[t] - total;  // global exclusive prefix at bin i0
  const unsigned char* prow = part + (size_t)(q * PART_BLOCKS + eb) * QUARTER;
  bool wrs = (eb == 0);
#pragma unroll
  for (int i = 0; i < PER; ++i) {
    int idx = i0 + i;
    if (idx < QUARTER) {
      cur[idx] = running + (int)prow[idx];
      if (wrs) row_start[qbase + idx] = running;
      running += lh[i];
    }
  }
  if (bk == 0 && t == 0) row_start[N_NODES] = N_EDGES;
  __syncthreads();

  int base0 = eb * EDGES_PER_PART;
#pragma unroll
  for (int s = 0; s < 3; ++s) {
    int off = s * 1024 + t * 4;
    if (off >= EDGES_PER_PART) break;
    int base = base0 + off;
    int4 ni = *reinterpret_cast<const int4*>(&node_idx[base]);
    int4 nb = *reinterpret_cast<const int4*>(&nbr_idx[base]);
    float4 wv = *reinterpret_cast<const float4*>(&ew[base]);
    unsigned d0 = (unsigned)(ni.x - qbase);
    unsigned d1 = (unsigned)(ni.y - qbase);
    unsigned d2 = (unsigned)(ni.z - qbase);
    unsigned d3 = (unsigned)(ni.w - qbase);
    if (d0 < QUARTER) {
      int p0 = atomicAdd(&cur[d0], 1);
      edge_s[p0] = pack_edge(nb.x, wv.x);
    }
    if (d1 < QUARTER) {
      int p1 = atomicAdd(&cur[d1], 1);
      edge_s[p1] = pack_edge(nb.y, wv.y);
    }
    if (d2 < QUARTER) {
      int p2 = atomicAdd(&cur[d2], 1);
      edge_s[p2] = pack_edge(nb.z, wv.z);
    }
    if (d3 < QUARTER) {
      int p3 = atomicAdd(&cur[d3], 1);
      edge_s[p3] = pack_edge(nb.w, wv.w);
    }
  }
}

// K4: fused spmm + update. grid = 1250 blocks x 256 thr, 8 rows/block.
// Phase 1: 32 thr/row = 4 edge-slices x 8 col-subs, 16 B fp8 gathers,
//   8-edge batches with next-batch edge prefetch (8 independent gathers in
//   flight per thread); packed 4 B edge records; HW cvt_pk_f32_fp8 dequant;
//   slice partials via f32 LDS scratch; agg f16 into swizzled tile rows 0..7.
// Phase 2 (4 waves): MFMA on a 16-row tile with rows 8-15 zero-padded;
//   U1/U2 output fragments split 2-per-wave.
__global__ __launch_bounds__(256) void spmm_update_kernel(
    const int* __restrict__ row_start, const unsigned* __restrict__ edge_s,
    const unsigned char* __restrict__ M8, const float* __restrict__ x,
    const _Float16* __restrict__ U1pk, const float* __restrict__ bu1,
    const _Float16* __restrict__ U2pk, const float* __restrict__ bu2,
    float* __restrict__ out) {
  __shared__ float scratch[3][8][128];
  __shared__ char tile[4096];
  int t = threadIdx.x;
  int row0 = blockIdx.x * 8;

  {
    int r = t >> 5;       // 0..7 local row
    int q = t & 31;
    int slice = q >> 3;   // 0..3
    int sub = q & 7;      // cols sub*16 .. sub*16+15
    int row = row0 + r;
    int s = row_start[row];
    int e_end = row_start[row + 1];
    float acc[16];
#pragma unroll
    for (int c = 0; c < 16; ++c) acc[c] = 0.f;
    const unsigned char* Mb = M8 + sub * 16;
    int base = s + slice * 8;
    unsigned pk[8];
#pragma unroll
    for (int k = 0; k < 8; ++k) {
      int e = base + k;
      pk[k] = edge_s[(e < e_end) ? e : s];
      if (e >= e_end) pk[k] &= 0xFFFF0000u;  // weight -> 0 for padded lanes
    }
    for (; base < e_end; base += 32) {
      unsigned pkn[8];
      int nb2 = base + 32;
#pragma unroll
      for (int k = 0; k < 8; ++k) {
        int e = nb2 + k;
        pkn[k] = edge_s[(e < e_end) ? e : s];
        if (e >= e_end) pkn[k] &= 0xFFFF0000u;
      }
      uint4 raw[8];
#pragma unroll
      for (int k = 0; k < 8; ++k)
        raw[k] = *reinterpret_cast<const uint4*>(Mb + (size_t)(pk[k] >> 16) * DIM);
#pragma unroll
      for (int k = 0; k < 8; ++k) {
        float w = __uint_as_float(pk[k] << 16);
        const unsigned* u32s = reinterpret_cast<const unsigned*>(&raw[k]);
#pragma unroll
        for (int qq = 0; qq < 4; ++qq) {
          auto f01 = __builtin_amdgcn_cvt_pk_f32_fp8(u32s[qq], false);
          auto f23 = __builtin_amdgcn_cvt_pk_f32_fp8(u32s[qq], true);
          acc[4 * qq + 0] = fmaf(w, f01[0], acc[4 * qq + 0]);
          acc[4 * qq + 1] = fmaf(w, f01[1], acc[4 * qq + 1]);
          acc[4 * qq + 2] = fmaf(w, f23[0], acc[4 * qq + 2]);
          acc[4 * qq + 3] = fmaf(w, f23[1], acc[4 * qq + 3]);
        }
      }
#pragma unroll
      for (int k = 0; k < 8; ++k) pk[k] = pkn[k];
    }
    if (slice >= 1) {
      float* dst = &scratch[slice - 1][r][sub * 16];
      *reinterpret_cast<float4*>(dst) = make_float4(acc[0], acc[1], acc[2], acc[3]);
      *reinterpret_cast<float4*>(dst + 4) = make_float4(acc[4], acc[5], acc[6], acc[7]);
      *reinterpret_cast<float4*>(dst + 8) = make_float4(acc[8], acc[9], acc[10], acc[11]);
      *reinterpret_cast<float4*>(dst + 12) = make_float4(acc[12], acc[13], acc[14], acc[15]);
    }
    __syncthreads();
    if (slice == 0) {
#pragma unroll
      for (int sl = 0; sl < 3; ++sl) {
        const float* src = &scratch[sl][r][sub * 16];
#pragma unroll
        for (int c = 0; c < 16; c += 4) {
          float4 o = *reinterpret_cast<const float4*>(src + c);
          acc[c] += o.x; acc[c + 1] += o.y; acc[c + 2] += o.z; acc[c + 3] += o.w;
        }
      }
      int cnt = e_end - s;
      float inv = 1.f / (float)(cnt > 0 ? cnt : 1);
      half8 hlo, hhi;
#pragma unroll
      for (int c = 0; c < 8; ++c) hlo[c] = (_Float16)(acc[c] * inv);
#pragma unroll
      for (int c = 0; c < 8; ++c) hhi[c] = (_Float16)(acc[8 + c] * inv);
      *reinterpret_cast<half8*>(tile + lds_swz(r, sub * 32)) = hlo;
      *reinterpret_cast<half8*>(tile + lds_swz(r, sub * 32 + 16)) = hhi;
    }
  }
  __syncthreads();

  int wid = t >> 6, lane = t & 63;
  int r = lane & 15, g = lane >> 4;
  half8 hzero;
#pragma unroll
  for (int i = 0; i < 8; ++i) hzero[i] = (_Float16)0.f;

  half8 a[8];
#pragma unroll
  for (int s = 0; s < 8; ++s) a[s] = hzero;
  if (r < 8) {
    const float* xp = x + (size_t)(row0 + r) * DIM;
#pragma unroll
    for (int s = 0; s < 4; ++s) {
      float4 lo = *reinterpret_cast<const float4*>(xp + s * 32 + g * 8);
      float4 hi = *reinterpret_cast<const float4*>(xp + s * 32 + g * 8 + 4);
      half8 h;
      h[0] = (_Float16)lo.x; h[1] = (_Float16)lo.y; h[2] = (_Float16)lo.z; h[3] = (_Float16)lo.w;
      h[4] = (_Float16)hi.x; h[5] = (_Float16)hi.y; h[6] = (_Float16)hi.z; h[7] = (_Float16)hi.w;
      a[s] = h;
    }
#pragma unroll
    for (int s = 0; s < 4; ++s)
      a[4 + s] = *reinterpret_cast<const half8*>(tile + lds_swz(r, (s * 32 + g * 8) * 2));
  }
  __syncthreads();  // agg-tile reads done before layer-1 overwrites tile

  f32x4 zero = {0.f, 0.f, 0.f, 0.f};
  {
    f32x4 acc1[2];
    acc1[0] = zero; acc1[1] = zero;
#pragma unroll
    for (int fi = 0; fi < 2; ++fi) {
      int f = wid * 2 + fi;
#pragma unroll
      for (int s = 0; s < 8; ++s) {
        half8 bfrag = *reinterpret_cast<const half8*>(U1pk + (size_t)((s * 8 + f) * 64 + lane) * 8);
        acc1[fi] = __builtin_amdgcn_mfma_f32_16x16x32_f16(a[s], bfrag, acc1[fi], 0, 0, 0);
      }
    }
#pragma unroll
    for (int fi = 0; fi < 2; ++fi) {
      int f = wid * 2 + fi;
      int col = f * 16 + r;
      float bv = bu1[col];
#pragma unroll
      for (int j = 0; j < 4; ++j) {
        int rl = g * 4 + j;
        float gv = gelu_exact(acc1[fi][j] + bv);
        *reinterpret_cast<_Float16*>(tile + lds_swz(rl, col * 2)) = (_Float16)gv;
      }
    }
  }
  __syncthreads();  // layer-1 tile complete before layer-2 reads

  {
    half8 a2[4];
#pragma unroll
    for (int s = 0; s < 4; ++s) a2[s] = hzero;
    if (r < 8) {
#pragma unroll
      for (int s = 0; s < 4; ++s)
        a2[s] = *reinterpret_cast<const half8*>(tile + lds_swz(r, (s * 32 + g * 8) * 2));
    }
    f32x4 acc2[2];
    acc2[0] = zero; acc2[1] = zero;
#pragma unroll
    for (int fi = 0; fi < 2; ++fi) {
      int f = wid * 2 + fi;
#pragma unroll
      for (int s = 0; s < 4; ++s) {
        half8 bfrag = *reinterpret_cast<const half8*>(U2pk + (size_t)((s * 8 + f) * 64 + lane) * 8);
        acc2[fi] = __builtin_amdgcn_mfma_f32_16x16x32_f16(a2[s], bfrag, acc2[fi], 0, 0, 0);
      }
    }
#pragma unroll
    for (int fi = 0; fi < 2; ++fi) {
      int f = wid * 2 + fi;
      int col = f * 16 + r;
      float bv = bu2[col];
#pragma unroll
      for (int j = 0; j < 4; ++j) {
        int rloc = g * 4 + j;
        if (rloc < 8)
          out[(size_t)(row0 + rloc) * DIM + col] = gelu_exact(acc2[fi][j] + bv);
      }
    }
  }
}

extern "C" void kernel_launch(void* const* d_in, const int* in_sizes, int n_in,
                              void* d_out, int out_size, void* d_ws, size_t ws_size,
                              hipStream_t stream) {
  const float* x = (const float*)d_in[0];
  const int* edges = (const int*)d_in[1];
  const float* ew = (const float*)d_in[2];

  const int* node_idx = edges;            // edges[0, :]
  const int* nbr_idx = edges + N_EDGES;   // edges[1, :]

  char* wsp = (char*)d_ws;
  auto alloc = [&](size_t bytes) {
    char* p = wsp;
    wsp += (bytes + 255) & ~(size_t)255;
    return p;
  };
  unsigned char* M8 = (unsigned char*)alloc((size_t)N_NODES * DIM);
  _Float16* W1pk = (_Float16*)alloc(128 * 128 * 2);
  _Float16* W2pk = (_Float16*)alloc(128 * 128 * 2);
  _Float16* U1pk = (_Float16*)alloc(256 * 128 * 2);
  _Float16* U2pk = (_Float16*)alloc(128 * 128 * 2);
  float* b1f = (float*)alloc(128 * 4);
  float* b2f = (float*)alloc(128 * 4);
  float* bu1 = (float*)alloc(128 * 4);
  float* bu2 = (float*)alloc(128 * 4);
  int* histq = (int*)alloc(4 * QPAD * 4);
  int* qtot = (int*)alloc(4 * 4);
  int* row_start = (int*)alloc((N_NODES + 1) * 4);
  unsigned char* part = (unsigned char*)alloc((size_t)PART_BLOCKS * N_NODES);
  unsigned* edge_s = (unsigned*)alloc((size_t)N_EDGES * 4);

  FoldAll fa;
  fa.g[0] = (const float*)d_in[3];  fa.bb[0] = (const float*)d_in[4];
  fa.m[0] = (const float*)d_in[5];  fa.v[0] = (const float*)d_in[6];
  fa.W[0] = (const float*)d_in[7];  fa.bias[0] = (const float*)d_in[8];
  fa.g[1] = (const float*)d_in[9];  fa.bb[1] = (const float*)d_in[10];
  fa.m[1] = (const float*)d_in[11]; fa.v[1] = (const float*)d_in[12];
  fa.W[1] = (const float*)d_in[13]; fa.bias[1] = (const float*)d_in[14];
  fa.g[2] = (const float*)d_in[15]; fa.bb[2] = (const float*)d_in[16];
  fa.m[2] = (const float*)d_in[17]; fa.v[2] = (const float*)d_in[18];
  fa.W[2] = (const float*)d_in[19]; fa.bias[2] = (const float*)d_in[20];
  fa.g[3] = (const float*)d_in[21]; fa.bb[3] = (const float*)d_in[22];
  fa.m[3] = (const float*)d_in[23]; fa.v[3] = (const float*)d_in[24];
  fa.W[3] = (const float*)d_in[25]; fa.bias[3] = (const float*)d_in[26];
  fa.pk[0] = W1pk; fa.pk[1] = W2pk; fa.pk[2] = U1pk; fa.pk[3] = U2pk;
  fa.bf[0] = b1f; fa.bf[1] = b2f; fa.bf[2] = bu1; fa.bf[3] = bu2;
  fa.din[0] = 128; fa.din[1] = 128; fa.din[2] = 256; fa.din[3] = 128;
  fa.S[0] = 4; fa.S[1] = 4; fa.S[2] = 8; fa.S[3] = 4;

  fold_hist_kernel<<<44 + PART_BLOCKS, 256, 0, stream>>>(fa, node_idx, part, histq, qtot);
  merge_msg_kernel<<<40 + MSG64_BLOCKS, 256, 0, stream>>>(
      part, histq, qtot, x, W1pk, b1f, W2pk, b2f, M8);
  scatter_kernel<<<SCAT_GRID, 256, 0, stream>>>(
      node_idx, nbr_idx, ew, histq, qtot, part, edge_s, row_start);
  spmm_update_kernel<<<SU_BLOCKS, 256, 0, stream>>>(
      row_start, edge_s, M8, x, U1pk, bu1, U2pk, bu2, (float*)d_out);
}